// Round 7
// baseline (162.748 us; speedup 1.0000x reference)
//
#include <hip/hip_runtime.h>

// HybridGeometryFeatures: B=2, N=12288, K=16 NN (excl self) + covariance eig features.
// knn: per (query, chunk of 768) branchless top-8 of quantized keys on
//      s = (|q|^2+|p|^2) - 2 q.p, with TWO independent run states (even/odd
//      batches) for 2x ILP, merged once at the end. Bit-identical result.
// feat: wave-per-query; exact f32 d2 recompute (difference form, bench-proven),
//       full bitonic sort-128 of u64 (d2bits<<32|idx) keys (2 elems/lane),
//       ballot-prefix compaction of first 16 non-self ranks, shuffle-reduced
//       centroid/cov + f64 eigensolve + features.
// ws: xs/ys/zs/ps (393KB) | cidx u16 [NQ][128] (6.3MB). Total 6.7MB.

#define NPTS 12288
#define NBATCH 2
#define NQ (NPTS * NBATCH)
#define KNN 16
#define NCH 16
#define CHSZ (NPTS / NCH) // 768
#define MKEEP 8
#define KBLK 128
#define QBLK (NQ / KBLK) // 192

typedef unsigned long long u64;
typedef unsigned short u16;
typedef unsigned int u32;

#define SWAPU(a, b) { u32 _lo = min(a, b); u32 _hi = max(a, b); a = _lo; b = _hi; }
#define DIST(dst, px, py, pz) { float _dx = Qx - (px); float _dy = Qy - (py); float _dz = Qz - (pz); \
                                dst = fmaf(_dz, _dz, fmaf(_dy, _dy, _dx * _dx)); }
#define KEY(kk, dd, rel) { kk = (__float_as_uint(dd) & 0xFFFFFC00u) | (u32)(rel); }

__device__ __forceinline__ u64 shfl_xor_u64(u64 v, int mask) {
  u32 lo = (u32)v, hi = (u32)(v >> 32);
  lo = (u32)__shfl_xor((int)lo, mask);
  hi = (u32)__shfl_xor((int)hi, mask);
  return ((u64)hi << 32) | lo;
}

__global__ __launch_bounds__(256) void pack_kernel(const float* __restrict__ xyz,
                                                   float* __restrict__ xs,
                                                   float* __restrict__ ys,
                                                   float* __restrict__ zs,
                                                   float* __restrict__ ps) {
  int i = blockIdx.x * 256 + threadIdx.x;
  if (i < NQ) {
    float x = xyz[3 * i + 0], y = xyz[3 * i + 1], z = xyz[3 * i + 2];
    xs[i] = x; ys[i] = y; zs[i] = z;
    ps[i] = fmaf(z, z, fmaf(y, y, x * x));
  }
}

// Process one batch of 8 candidates into run r[0..7] (ascending quantized keys).
__device__ __forceinline__ void batch8(u32 (&r)[8],
                                       const float4* lx4, const float4* ly4,
                                       const float4* lz4, const float4* lp4,
                                       int c0, float m2x, float m2y, float m2z, float qq) {
  int i4 = c0 >> 2;
  float4 xA = lx4[i4], xB = lx4[i4 + 1];
  float4 yA = ly4[i4], yB = ly4[i4 + 1];
  float4 zA = lz4[i4], zB = lz4[i4 + 1];
  float4 pA = lp4[i4], pB = lp4[i4 + 1];
#define SVAL(dst, px, py, pz, pp) dst = fmaf(m2x, (px), fmaf(m2y, (py), fmaf(m2z, (pz), qq + (pp))));
  float e0, e1, e2, e3, e4, e5, e6, e7;
  SVAL(e0, xA.x, yA.x, zA.x, pA.x) SVAL(e1, xA.y, yA.y, zA.y, pA.y)
  SVAL(e2, xA.z, yA.z, zA.z, pA.z) SVAL(e3, xA.w, yA.w, zA.w, pA.w)
  SVAL(e4, xB.x, yB.x, zB.x, pB.x) SVAL(e5, xB.y, yB.y, zB.y, pB.y)
  SVAL(e6, xB.z, yB.z, zB.z, pB.z) SVAL(e7, xB.w, yB.w, zB.w, pB.w)
#undef SVAL
  u32 d0, d1, d2, d3, d4, d5, d6, d7;
  KEY(d0, e0, c0 + 0); KEY(d1, e1, c0 + 1); KEY(d2, e2, c0 + 2); KEY(d3, e3, c0 + 3);
  KEY(d4, e4, c0 + 4); KEY(d5, e5, c0 + 5); KEY(d6, e6, c0 + 6); KEY(d7, e7, c0 + 7);
  // Batcher sort-8 ascending (19 CEs)
  SWAPU(d0, d1) SWAPU(d2, d3) SWAPU(d4, d5) SWAPU(d6, d7)
  SWAPU(d0, d2) SWAPU(d1, d3) SWAPU(d4, d6) SWAPU(d5, d7)
  SWAPU(d1, d2) SWAPU(d5, d6)
  SWAPU(d0, d4) SWAPU(d1, d5) SWAPU(d2, d6) SWAPU(d3, d7)
  SWAPU(d2, d4) SWAPU(d3, d5)
  SWAPU(d1, d2) SWAPU(d3, d4) SWAPU(d5, d6)
  // keep lowest-8 of (run, batch): cross-min -> bitonic resort (12 CEs)
  u32 m0 = min(r[0], d7), m1 = min(r[1], d6), m2 = min(r[2], d5), m3 = min(r[3], d4);
  u32 m4 = min(r[4], d3), m5 = min(r[5], d2), m6 = min(r[6], d1), m7 = min(r[7], d0);
  SWAPU(m0, m4) SWAPU(m1, m5) SWAPU(m2, m6) SWAPU(m3, m7)
  SWAPU(m0, m2) SWAPU(m1, m3) SWAPU(m4, m6) SWAPU(m5, m7)
  SWAPU(m0, m1) SWAPU(m2, m3) SWAPU(m4, m5) SWAPU(m6, m7)
  r[0] = m0; r[1] = m1; r[2] = m2; r[3] = m3; r[4] = m4; r[5] = m5; r[6] = m6; r[7] = m7;
}

// One thread = one query x one chunk of 768. Two independent run states
// (even/odd batches) interleaved for ILP; exact merge at the end.
__global__ __launch_bounds__(KBLK) void knn_kernel(const float* __restrict__ xs,
                                                   const float* __restrict__ ys,
                                                   const float* __restrict__ zs,
                                                   const float* __restrict__ ps,
                                                   u16* __restrict__ cidx) {
  int bid = blockIdx.x;
  int qb = bid % QBLK;
  int ch = bid / QBLK;
  int q = qb * KBLK + threadIdx.x;
  int b = q / NPTS; // uniform per block (NPTS % KBLK == 0)
  int base = b * NPTS + ch * CHSZ;

  __shared__ __align__(16) float lx[CHSZ + 8];
  __shared__ __align__(16) float ly[CHSZ + 8];
  __shared__ __align__(16) float lz[CHSZ + 8];
  __shared__ __align__(16) float lp[CHSZ + 8];
  {
    float4* sx = (float4*)lx; float4* sy = (float4*)ly;
    float4* sz = (float4*)lz; float4* sp = (float4*)lp;
    const float4* gx = (const float4*)(xs + base);
    const float4* gy = (const float4*)(ys + base);
    const float4* gz = (const float4*)(zs + base);
    const float4* gp = (const float4*)(ps + base);
    for (int i = threadIdx.x; i < CHSZ / 4; i += KBLK) {
      sx[i] = gx[i]; sy[i] = gy[i]; sz[i] = gz[i]; sp[i] = gp[i];
    }
  }
  __syncthreads();

  float Qx = xs[q], Qy = ys[q], Qz = zs[q];
  float qq = fmaf(Qz, Qz, fmaf(Qy, Qy, Qx * Qx));
  float m2x = -2.0f * Qx, m2y = -2.0f * Qy, m2z = -2.0f * Qz;

  u32 rA[8], rB[8];
#pragma unroll
  for (int j = 0; j < 8; ++j) { rA[j] = ~0u; rB[j] = ~0u; }

  const float4* lx4 = (const float4*)lx;
  const float4* ly4 = (const float4*)ly;
  const float4* lz4 = (const float4*)lz;
  const float4* lp4 = (const float4*)lp;

#pragma unroll 1
  for (int c0 = 0; c0 < CHSZ; c0 += 16) {
    batch8(rA, lx4, ly4, lz4, lp4, c0, m2x, m2y, m2z, qq);
    batch8(rB, lx4, ly4, lz4, lp4, c0 + 8, m2x, m2y, m2z, qq);
  }

  // exact final merge: lowest-8 of (rA asc, rB asc)
  u32 m0 = min(rA[0], rB[7]), m1 = min(rA[1], rB[6]);
  u32 m2 = min(rA[2], rB[5]), m3 = min(rA[3], rB[4]);
  u32 m4 = min(rA[4], rB[3]), m5 = min(rA[5], rB[2]);
  u32 m6 = min(rA[6], rB[1]), m7 = min(rA[7], rB[0]);
  SWAPU(m0, m4) SWAPU(m1, m5) SWAPU(m2, m6) SWAPU(m3, m7)
  SWAPU(m0, m2) SWAPU(m1, m3) SWAPU(m4, m6) SWAPU(m5, m7)
  SWAPU(m0, m1) SWAPU(m2, m3) SWAPU(m4, m5) SWAPU(m6, m7)

  // epilogue: strip to global-in-batch indices, pack 8 x u16 = 16B store
  u32 cb = (u32)(ch * CHSZ);
  uint4 w;
  w.x = (cb + (m0 & 1023u)) | ((cb + (m1 & 1023u)) << 16);
  w.y = (cb + (m2 & 1023u)) | ((cb + (m3 & 1023u)) << 16);
  w.z = (cb + (m4 & 1023u)) | ((cb + (m5 & 1023u)) << 16);
  w.w = (cb + (m6 & 1023u)) | ((cb + (m7 & 1023u)) << 16);
  *(uint4*)(cidx + (size_t)q * (NCH * MKEEP) + ch * MKEEP) = w;
}

// One wave per query: exact d2 recompute for lane's 2 candidates; full bitonic
// sort-128 of u64 keys (element i = 2*lane+slot); first-16-non-self compaction;
// covariance + f64 eigensolve + features (all lanes replicated, lane 0 writes).
__global__ __launch_bounds__(256) void feat_kernel(const float* __restrict__ xs,
                                                   const float* __restrict__ ys,
                                                   const float* __restrict__ zs,
                                                   const float* __restrict__ normals,
                                                   const u16* __restrict__ cidx,
                                                   float* __restrict__ out) {
  __shared__ u32 selidx[4][16];
  int wid = threadIdx.x >> 6;
  int lane = threadIdx.x & 63;
  int t = blockIdx.x * 4 + wid; // query 0..NQ
  int b = t / NPTS;
  int qi = t - b * NPTS;
  int bbase = b * NPTS;

  float Qx = xs[t], Qy = ys[t], Qz = zs[t];

  // lane's two candidates (one u32 load = 2 u16, coalesced)
  u32 pair = ((const u32*)(cidx + (size_t)t * (NCH * MKEEP)))[lane];
  int ia = (int)(pair & 0xFFFFu);
  int ib = (int)(pair >> 16);
  float dA, dB;
  DIST(dA, xs[bbase + ia], ys[bbase + ia], zs[bbase + ia]);
  DIST(dB, xs[bbase + ib], ys[bbase + ib], zs[bbase + ib]);
  u64 e0 = ((u64)__float_as_uint(dA) << 32) | (u32)ia;
  u64 e1 = ((u64)__float_as_uint(dB) << 32) | (u32)ib;

  // bitonic sort of 128 elements ascending; element index i = 2*lane + slot.
#pragma unroll
  for (int k = 2; k <= 128; k <<= 1) {
#pragma unroll
    for (int j = k >> 1; j > 0; j >>= 1) {
      if (j >= 2) {
        int h = j >> 1; // lane-xor distance (1..32)
        u64 p0 = shfl_xor_u64(e0, h);
        u64 p1 = shfl_xor_u64(e1, h);
        bool wantmin = (((lane & h) == 0) == (((2 * lane) & k) == 0));
        e0 = wantmin ? (p0 < e0 ? p0 : e0) : (p0 > e0 ? p0 : e0);
        e1 = wantmin ? (p1 < e1 ? p1 : e1) : (p1 > e1 ? p1 : e1);
      } else {
        bool asc = (((2 * lane) & k) == 0);
        u64 mn = e0 < e1 ? e0 : e1;
        u64 mx = e0 < e1 ? e1 : e0;
        e0 = asc ? mn : mx;
        e1 = asc ? mx : mn;
      }
    }
  }

  // compact first 16 non-self ranks into LDS (rank of slot s at lane l = 2l+s)
  u32 i0 = (u32)e0 & 0xFFFFu;
  u32 i1 = (u32)e1 & 0xFFFFu;
  bool f0 = (int)i0 != qi;
  bool f1 = (int)i1 != qi;
  u64 b0 = __ballot(f0);
  u64 b1 = __ballot(f1);
  u64 lm = lane ? (~0ull >> (64 - lane)) : 0ull;
  int pre0 = __popcll(b0 & lm) + __popcll(b1 & lm);
  int pre1 = pre0 + (f0 ? 1 : 0);
  if (f0 && pre0 < KNN) selidx[wid][pre0] = i0;
  if (f1 && pre1 < KNN) selidx[wid][pre1] = i1;
  __syncthreads();

  int nidx = selidx[wid][lane & 15];
  float px = xs[bbase + nidx];
  float py = ys[bbase + nidx];
  float pz = zs[bbase + nidx];

  // centroid over each 16-lane group (all groups hold identical data)
  float sx = px, sy = py, sz = pz;
  sx += __shfl_xor(sx, 1); sy += __shfl_xor(sy, 1); sz += __shfl_xor(sz, 1);
  sx += __shfl_xor(sx, 2); sy += __shfl_xor(sy, 2); sz += __shfl_xor(sz, 2);
  sx += __shfl_xor(sx, 4); sy += __shfl_xor(sy, 4); sz += __shfl_xor(sz, 4);
  sx += __shfl_xor(sx, 8); sy += __shfl_xor(sy, 8); sz += __shfl_xor(sz, 8);
  const float invK = 1.0f / 16.0f;
  float cx = sx * invK, cy = sy * invK, cz = sz * invK;

  float dx = px - cx, dy = py - cy, dz = pz - cz;
  float c00 = dx * dx, c01 = dx * dy, c02 = dx * dz;
  float c11 = dy * dy, c12 = dy * dz, c22 = dz * dz;
#pragma unroll
  for (int m = 1; m <= 8; m <<= 1) {
    c00 += __shfl_xor(c00, m); c01 += __shfl_xor(c01, m); c02 += __shfl_xor(c02, m);
    c11 += __shfl_xor(c11, m); c12 += __shfl_xor(c12, m); c22 += __shfl_xor(c22, m);
  }
  const float inv15 = 1.0f / 15.0f;
  c00 *= inv15; c01 *= inv15; c02 *= inv15;
  c11 *= inv15; c12 *= inv15; c22 *= inv15;

  // f64 analytic eigensolve (smallest eigenvalue) — proven path.
  double a00 = c00, a01 = c01, a02 = c02, a11 = c11, a12 = c12, a22 = c22;
  double tr = a00 + a11 + a22;
  double qm = tr * (1.0 / 3.0);
  double p1 = a01 * a01 + a02 * a02 + a12 * a12;
  double b00 = a00 - qm, b11 = a11 - qm, b22 = a22 - qm;
  double p2 = b00 * b00 + b11 * b11 + b22 * b22 + 2.0 * p1;
  double lmin = qm;
  if (p2 > 0.0) {
    double p = sqrt(p2 * (1.0 / 6.0));
    double ip = 1.0 / p;
    double q00 = b00 * ip, q01 = a01 * ip, q02 = a02 * ip;
    double q11 = b11 * ip, q12 = a12 * ip, q22 = b22 * ip;
    double det = q00 * (q11 * q22 - q12 * q12) - q01 * (q01 * q22 - q12 * q02) +
                 q02 * (q01 * q12 - q11 * q02);
    double r = 0.5 * det;
    r = r < -1.0 ? -1.0 : (r > 1.0 ? 1.0 : r);
    double phi = acos(r) * (1.0 / 3.0);
    lmin = qm + 2.0 * p * cos(phi + 2.0943951023931953);
  }

  // eigenvector: cross products of rows of (A - lmin I), pick largest.
  double m00 = a00 - lmin, m11 = a11 - lmin, m22 = a22 - lmin;
  double v0x = a01 * a12 - a02 * m11;
  double v0y = a02 * a01 - m00 * a12;
  double v0z = m00 * m11 - a01 * a01;
  double v1x = a01 * m22 - a02 * a12;
  double v1y = a02 * a02 - m00 * m22;
  double v1z = m00 * a12 - a01 * a02;
  double v2x = m11 * m22 - a12 * a12;
  double v2y = a12 * a02 - a01 * m22;
  double v2z = a01 * a12 - m11 * a02;
  double n0 = v0x * v0x + v0y * v0y + v0z * v0z;
  double n1 = v1x * v1x + v1y * v1y + v1z * v1z;
  double n2 = v2x * v2x + v2y * v2y + v2z * v2z;
  double vx, vy, vz, nn;
  if (n0 >= n1 && n0 >= n2) { vx = v0x; vy = v0y; vz = v0z; nn = n0; }
  else if (n1 >= n2)        { vx = v1x; vy = v1y; vz = v1z; nn = n1; }
  else                      { vx = v2x; vy = v2y; vz = v2z; nn = n2; }
  if (nn < 1e-60) { vx = 0.0; vy = 0.0; vz = 1.0; nn = 1.0; }
  double inn = 1.0 / sqrt(nn);
  float vxf = (float)(vx * inn), vyf = (float)(vy * inn), vzf = (float)(vz * inn);

  // roughness: mean |centered . v| over the 16-lane group
  float s = fabsf(dx * vxf + dy * vyf + dz * vzf);
  s += __shfl_xor(s, 1);
  s += __shfl_xor(s, 2);
  s += __shfl_xor(s, 4);
  s += __shfl_xor(s, 8);

  if (lane == 0) {
    float nrx = normals[3 * (size_t)t + 0];
    float nry = normals[3 * (size_t)t + 1];
    float nrz = normals[3 * (size_t)t + 2];
    float dot = vxf * nrx + vyf * nry + vzf * nrz;
    float cons = fabsf(dot);
    float trf = c00 + c11 + c22;
    float curv = (float)lmin / fmaxf(trf, 1e-8f);
    float* o = out + (size_t)t * 6;
    o[0] = cons;
    o[1] = nrx;
    o[2] = nry;
    o[3] = nrz;
    o[4] = curv;
    o[5] = s * invK;
  }
}

extern "C" void kernel_launch(void* const* d_in, const int* in_sizes, int n_in,
                              void* d_out, int out_size, void* d_ws, size_t ws_size,
                              hipStream_t stream) {
  const float* xyz = (const float*)d_in[0];
  const float* normals = (const float*)d_in[1];
  float* out = (float*)d_out;

  float* xs = (float*)d_ws;
  float* ys = xs + NQ;
  float* zs = ys + NQ;
  float* ps = zs + NQ;
  u16* cidx = (u16*)(ps + NQ); // NQ*128 u16 = 6.3MB

  pack_kernel<<<NQ / 256, 256, 0, stream>>>(xyz, xs, ys, zs, ps);
  knn_kernel<<<QBLK * NCH, KBLK, 0, stream>>>(xs, ys, zs, ps, cidx);
  feat_kernel<<<NQ / 4, 256, 0, stream>>>(xs, ys, zs, normals, cidx, out);
}

// Round 8
// 155.294 us; speedup vs baseline: 1.0480x; 1.0480x over previous
//
#include <hip/hip_runtime.h>

// HybridGeometryFeatures: B=2, N=12288, K=16 NN (excl self) + covariance eig features.
// knn: one thread = (query, chunk of 768). Candidate reads are WAVE-UNIFORM ->
//      scalar-pipe s_load from global AoS float4(x,y,z,|p|^2); NO LDS (the LDS
//      pipe, 1/CU, was the r5-r7 bottleneck at ~92us). Branchless top-8 of
//      quantized keys  key = (bits(s) & 0xFFFFFC00) | relidx,
//      s = (|q|^2+|p|^2) - 2 q.p. Bit-identical selection to rounds 5/7.
// feat: wave-per-query; exact f32 d2 recompute (difference form, bench-proven),
//       bitonic sort-128 of u64 (d2bits<<32|idx), first-16-non-self compaction,
//       shuffle-reduced centroid/cov + f64 eigensolve + features.
// ws: xs/ys/zs (295KB) | pts4 AoS + 128B pad (393KB) | cidx u16 [NQ][128] (6.3MB).

#define NPTS 12288
#define NBATCH 2
#define NQ (NPTS * NBATCH)
#define KNN 16
#define NCH 16
#define CHSZ (NPTS / NCH) // 768
#define MKEEP 8
#define QBLK (NQ / 256) // 96

typedef unsigned long long u64;
typedef unsigned short u16;
typedef unsigned int u32;

#define SWAPU(a, b) { u32 _lo = min(a, b); u32 _hi = max(a, b); a = _lo; b = _hi; }
#define DIST(dst, px, py, pz) { float _dx = Qx - (px); float _dy = Qy - (py); float _dz = Qz - (pz); \
                                dst = fmaf(_dz, _dz, fmaf(_dy, _dy, _dx * _dx)); }
#define KEY(kk, dd, rel) { kk = (__float_as_uint(dd) & 0xFFFFFC00u) | (u32)(rel); }

__device__ __forceinline__ u64 shfl_xor_u64(u64 v, int mask) {
  u32 lo = (u32)v, hi = (u32)(v >> 32);
  lo = (u32)__shfl_xor((int)lo, mask);
  hi = (u32)__shfl_xor((int)hi, mask);
  return ((u64)hi << 32) | lo;
}

__global__ __launch_bounds__(256) void pack_kernel(const float* __restrict__ xyz,
                                                   float* __restrict__ xs,
                                                   float* __restrict__ ys,
                                                   float* __restrict__ zs,
                                                   float4* __restrict__ pts4) {
  int i = blockIdx.x * 256 + threadIdx.x;
  if (i < NQ) {
    float x = xyz[3 * i + 0], y = xyz[3 * i + 1], z = xyz[3 * i + 2];
    xs[i] = x; ys[i] = y; zs[i] = z;
    pts4[i] = make_float4(x, y, z, fmaf(z, z, fmaf(y, y, x * x)));
  }
}

// One thread = one query x one chunk of 768 candidates. Candidate loads are
// uniform (blockIdx-derived address only) -> scalar pipe. Branchless top-8.
__global__ __launch_bounds__(256) void knn_kernel(const float4* __restrict__ pts4,
                                                  u16* __restrict__ cidx) {
  int bid = blockIdx.x;
  int qb = bid % QBLK;
  int chk = bid / QBLK;
  int q0 = qb * 256;                    // uniform
  int b = q0 / NPTS;                    // uniform (NPTS % 256 == 0)
  int base = b * NPTS + chk * CHSZ;     // uniform
  int q = q0 + threadIdx.x;

  float4 Q = pts4[q];                   // per-lane: x,y,z,|q|^2
  float qq = Q.w;
  float m2x = -2.0f * Q.x, m2y = -2.0f * Q.y, m2z = -2.0f * Q.z;

  const float4* cp = pts4 + base;       // uniform pointer

  u32 r0 = ~0u, r1 = ~0u, r2 = ~0u, r3 = ~0u, r4 = ~0u, r5 = ~0u, r6 = ~0u, r7 = ~0u;

#define SVAL(dst, c) dst = fmaf(m2x, (c).x, fmaf(m2y, (c).y, fmaf(m2z, (c).z, qq + (c).w)));

  // prime batch 0 (uniform loads -> SGPRs)
  float4 a0 = cp[0], a1 = cp[1], a2 = cp[2], a3 = cp[3];
  float4 a4 = cp[4], a5 = cp[5], a6 = cp[6], a7 = cp[7];

#pragma unroll 1
  for (int c0 = 0; c0 < CHSZ; c0 += 8) {
    // prefetch next batch (last iter overreads into the 128B pad)
    float4 n0 = cp[c0 + 8], n1 = cp[c0 + 9], n2 = cp[c0 + 10], n3 = cp[c0 + 11];
    float4 n4 = cp[c0 + 12], n5 = cp[c0 + 13], n6 = cp[c0 + 14], n7 = cp[c0 + 15];

    float e0, e1, e2, e3, e4, e5, e6, e7;
    SVAL(e0, a0) SVAL(e1, a1) SVAL(e2, a2) SVAL(e3, a3)
    SVAL(e4, a4) SVAL(e5, a5) SVAL(e6, a6) SVAL(e7, a7)
    u32 d0, d1, d2, d3, d4, d5, d6, d7;
    KEY(d0, e0, c0 + 0); KEY(d1, e1, c0 + 1); KEY(d2, e2, c0 + 2); KEY(d3, e3, c0 + 3);
    KEY(d4, e4, c0 + 4); KEY(d5, e5, c0 + 5); KEY(d6, e6, c0 + 6); KEY(d7, e7, c0 + 7);
    // Batcher sort-8 ascending (19 CEs)
    SWAPU(d0, d1) SWAPU(d2, d3) SWAPU(d4, d5) SWAPU(d6, d7)
    SWAPU(d0, d2) SWAPU(d1, d3) SWAPU(d4, d6) SWAPU(d5, d7)
    SWAPU(d1, d2) SWAPU(d5, d6)
    SWAPU(d0, d4) SWAPU(d1, d5) SWAPU(d2, d6) SWAPU(d3, d7)
    SWAPU(d2, d4) SWAPU(d3, d5)
    SWAPU(d1, d2) SWAPU(d3, d4) SWAPU(d5, d6)
    // keep lowest-8 of (run, batch): cross-min -> bitonic resort (12 CEs)
    u32 m0 = min(r0, d7), m1 = min(r1, d6), m2 = min(r2, d5), m3 = min(r3, d4);
    u32 m4 = min(r4, d3), m5 = min(r5, d2), m6 = min(r6, d1), m7 = min(r7, d0);
    SWAPU(m0, m4) SWAPU(m1, m5) SWAPU(m2, m6) SWAPU(m3, m7)
    SWAPU(m0, m2) SWAPU(m1, m3) SWAPU(m4, m6) SWAPU(m5, m7)
    SWAPU(m0, m1) SWAPU(m2, m3) SWAPU(m4, m5) SWAPU(m6, m7)
    r0 = m0; r1 = m1; r2 = m2; r3 = m3; r4 = m4; r5 = m5; r6 = m6; r7 = m7;

    a0 = n0; a1 = n1; a2 = n2; a3 = n3; a4 = n4; a5 = n5; a6 = n6; a7 = n7;
  }
#undef SVAL

  // epilogue: strip to global-in-batch indices, pack 8 x u16 = 16B store
  u32 cb = (u32)(chk * CHSZ);
  uint4 w;
  w.x = (cb + (r0 & 1023u)) | ((cb + (r1 & 1023u)) << 16);
  w.y = (cb + (r2 & 1023u)) | ((cb + (r3 & 1023u)) << 16);
  w.z = (cb + (r4 & 1023u)) | ((cb + (r5 & 1023u)) << 16);
  w.w = (cb + (r6 & 1023u)) | ((cb + (r7 & 1023u)) << 16);
  *(uint4*)(cidx + (size_t)q * (NCH * MKEEP) + chk * MKEEP) = w;
}

// One wave per query: exact d2 recompute for lane's 2 candidates; full bitonic
// sort-128 of u64 keys (element i = 2*lane+slot); first-16-non-self compaction;
// covariance + f64 eigensolve + features (all lanes replicated, lane 0 writes).
__global__ __launch_bounds__(256) void feat_kernel(const float* __restrict__ xs,
                                                   const float* __restrict__ ys,
                                                   const float* __restrict__ zs,
                                                   const float* __restrict__ normals,
                                                   const u16* __restrict__ cidx,
                                                   float* __restrict__ out) {
  __shared__ u32 selidx[4][16];
  int wid = threadIdx.x >> 6;
  int lane = threadIdx.x & 63;
  int t = blockIdx.x * 4 + wid; // query 0..NQ
  int b = t / NPTS;
  int qi = t - b * NPTS;
  int bbase = b * NPTS;

  float Qx = xs[t], Qy = ys[t], Qz = zs[t];

  // lane's two candidates (one u32 load = 2 u16, coalesced)
  u32 pair = ((const u32*)(cidx + (size_t)t * (NCH * MKEEP)))[lane];
  int ia = (int)(pair & 0xFFFFu);
  int ib = (int)(pair >> 16);
  float dA, dB;
  DIST(dA, xs[bbase + ia], ys[bbase + ia], zs[bbase + ia]);
  DIST(dB, xs[bbase + ib], ys[bbase + ib], zs[bbase + ib]);
  u64 e0 = ((u64)__float_as_uint(dA) << 32) | (u32)ia;
  u64 e1 = ((u64)__float_as_uint(dB) << 32) | (u32)ib;

  // bitonic sort of 128 elements ascending; element index i = 2*lane + slot.
#pragma unroll
  for (int k = 2; k <= 128; k <<= 1) {
#pragma unroll
    for (int j = k >> 1; j > 0; j >>= 1) {
      if (j >= 2) {
        int h = j >> 1; // lane-xor distance (1..32)
        u64 p0 = shfl_xor_u64(e0, h);
        u64 p1 = shfl_xor_u64(e1, h);
        bool wantmin = (((lane & h) == 0) == (((2 * lane) & k) == 0));
        e0 = wantmin ? (p0 < e0 ? p0 : e0) : (p0 > e0 ? p0 : e0);
        e1 = wantmin ? (p1 < e1 ? p1 : e1) : (p1 > e1 ? p1 : e1);
      } else {
        bool asc = (((2 * lane) & k) == 0);
        u64 mn = e0 < e1 ? e0 : e1;
        u64 mx = e0 < e1 ? e1 : e0;
        e0 = asc ? mn : mx;
        e1 = asc ? mx : mn;
      }
    }
  }

  // compact first 16 non-self ranks into LDS (rank of slot s at lane l = 2l+s)
  u32 i0 = (u32)e0 & 0xFFFFu;
  u32 i1 = (u32)e1 & 0xFFFFu;
  bool f0 = (int)i0 != qi;
  bool f1 = (int)i1 != qi;
  u64 b0 = __ballot(f0);
  u64 b1 = __ballot(f1);
  u64 lm = lane ? (~0ull >> (64 - lane)) : 0ull;
  int pre0 = __popcll(b0 & lm) + __popcll(b1 & lm);
  int pre1 = pre0 + (f0 ? 1 : 0);
  if (f0 && pre0 < KNN) selidx[wid][pre0] = i0;
  if (f1 && pre1 < KNN) selidx[wid][pre1] = i1;
  __syncthreads();

  int nidx = selidx[wid][lane & 15];
  float px = xs[bbase + nidx];
  float py = ys[bbase + nidx];
  float pz = zs[bbase + nidx];

  // centroid over each 16-lane group (all groups hold identical data)
  float sx = px, sy = py, sz = pz;
  sx += __shfl_xor(sx, 1); sy += __shfl_xor(sy, 1); sz += __shfl_xor(sz, 1);
  sx += __shfl_xor(sx, 2); sy += __shfl_xor(sy, 2); sz += __shfl_xor(sz, 2);
  sx += __shfl_xor(sx, 4); sy += __shfl_xor(sy, 4); sz += __shfl_xor(sz, 4);
  sx += __shfl_xor(sx, 8); sy += __shfl_xor(sy, 8); sz += __shfl_xor(sz, 8);
  const float invK = 1.0f / 16.0f;
  float cx = sx * invK, cy = sy * invK, cz = sz * invK;

  float dx = px - cx, dy = py - cy, dz = pz - cz;
  float c00 = dx * dx, c01 = dx * dy, c02 = dx * dz;
  float c11 = dy * dy, c12 = dy * dz, c22 = dz * dz;
#pragma unroll
  for (int m = 1; m <= 8; m <<= 1) {
    c00 += __shfl_xor(c00, m); c01 += __shfl_xor(c01, m); c02 += __shfl_xor(c02, m);
    c11 += __shfl_xor(c11, m); c12 += __shfl_xor(c12, m); c22 += __shfl_xor(c22, m);
  }
  const float inv15 = 1.0f / 15.0f;
  c00 *= inv15; c01 *= inv15; c02 *= inv15;
  c11 *= inv15; c12 *= inv15; c22 *= inv15;

  // f64 analytic eigensolve (smallest eigenvalue) — proven path.
  double a00 = c00, a01 = c01, a02 = c02, a11 = c11, a12 = c12, a22 = c22;
  double tr = a00 + a11 + a22;
  double qm = tr * (1.0 / 3.0);
  double p1 = a01 * a01 + a02 * a02 + a12 * a12;
  double b00 = a00 - qm, b11 = a11 - qm, b22 = a22 - qm;
  double p2 = b00 * b00 + b11 * b11 + b22 * b22 + 2.0 * p1;
  double lmin = qm;
  if (p2 > 0.0) {
    double p = sqrt(p2 * (1.0 / 6.0));
    double ip = 1.0 / p;
    double q00 = b00 * ip, q01 = a01 * ip, q02 = a02 * ip;
    double q11 = b11 * ip, q12 = a12 * ip, q22 = b22 * ip;
    double det = q00 * (q11 * q22 - q12 * q12) - q01 * (q01 * q22 - q12 * q02) +
                 q02 * (q01 * q12 - q11 * q02);
    double r = 0.5 * det;
    r = r < -1.0 ? -1.0 : (r > 1.0 ? 1.0 : r);
    double phi = acos(r) * (1.0 / 3.0);
    lmin = qm + 2.0 * p * cos(phi + 2.0943951023931953);
  }

  // eigenvector: cross products of rows of (A - lmin I), pick largest.
  double m00 = a00 - lmin, m11 = a11 - lmin, m22 = a22 - lmin;
  double v0x = a01 * a12 - a02 * m11;
  double v0y = a02 * a01 - m00 * a12;
  double v0z = m00 * m11 - a01 * a01;
  double v1x = a01 * m22 - a02 * a12;
  double v1y = a02 * a02 - m00 * m22;
  double v1z = m00 * a12 - a01 * a02;
  double v2x = m11 * m22 - a12 * a12;
  double v2y = a12 * a02 - a01 * m22;
  double v2z = a01 * a12 - m11 * a02;
  double n0 = v0x * v0x + v0y * v0y + v0z * v0z;
  double n1 = v1x * v1x + v1y * v1y + v1z * v1z;
  double n2 = v2x * v2x + v2y * v2y + v2z * v2z;
  double vx, vy, vz, nn;
  if (n0 >= n1 && n0 >= n2) { vx = v0x; vy = v0y; vz = v0z; nn = n0; }
  else if (n1 >= n2)        { vx = v1x; vy = v1y; vz = v1z; nn = n1; }
  else                      { vx = v2x; vy = v2y; vz = v2z; nn = n2; }
  if (nn < 1e-60) { vx = 0.0; vy = 0.0; vz = 1.0; nn = 1.0; }
  double inn = 1.0 / sqrt(nn);
  float vxf = (float)(vx * inn), vyf = (float)(vy * inn), vzf = (float)(vz * inn);

  // roughness: mean |centered . v| over the 16-lane group
  float s = fabsf(dx * vxf + dy * vyf + dz * vzf);
  s += __shfl_xor(s, 1);
  s += __shfl_xor(s, 2);
  s += __shfl_xor(s, 4);
  s += __shfl_xor(s, 8);

  if (lane == 0) {
    float nrx = normals[3 * (size_t)t + 0];
    float nry = normals[3 * (size_t)t + 1];
    float nrz = normals[3 * (size_t)t + 2];
    float dot = vxf * nrx + vyf * nry + vzf * nrz;
    float cons = fabsf(dot);
    float trf = c00 + c11 + c22;
    float curv = (float)lmin / fmaxf(trf, 1e-8f);
    float* o = out + (size_t)t * 6;
    o[0] = cons;
    o[1] = nrx;
    o[2] = nry;
    o[3] = nrz;
    o[4] = curv;
    o[5] = s * invK;
  }
}

extern "C" void kernel_launch(void* const* d_in, const int* in_sizes, int n_in,
                              void* d_out, int out_size, void* d_ws, size_t ws_size,
                              hipStream_t stream) {
  const float* xyz = (const float*)d_in[0];
  const float* normals = (const float*)d_in[1];
  float* out = (float*)d_out;

  float* xs = (float*)d_ws;
  float* ys = xs + NQ;
  float* zs = ys + NQ;
  float4* pts4 = (float4*)(zs + NQ);          // NQ float4 + 8 pad
  u16* cidx = (u16*)(pts4 + NQ + 8);          // NQ*128 u16 = 6.3MB

  pack_kernel<<<NQ / 256, 256, 0, stream>>>(xyz, xs, ys, zs, pts4);
  knn_kernel<<<QBLK * NCH, 256, 0, stream>>>(pts4, cidx);
  feat_kernel<<<NQ / 4, 256, 0, stream>>>(xs, ys, zs, normals, cidx, out);
}

// Round 9
// 145.707 us; speedup vs baseline: 1.1170x; 1.0658x over previous
//
#include <hip/hip_runtime.h>

// HybridGeometryFeatures: B=2, N=12288, K=16 NN (excl self) + covariance eig features.
// knn: one thread = (query, chunk of 768). Candidate reads WAVE-UNIFORM ->
//      scalar pipe (s_load) from AoS float4(x,y,z,|p|^2); no LDS. Branchless
//      top-8 of quantized keys key=(bits(s)&0xFFFFFC00)|relidx,
//      s = (|q|^2+|p|^2) - 2 q.p. (r8-proven, 110us)
// feat: one THREAD per query (no shuffles/LDS — r8's wave version was
//       LDS-pipe-bound via ds_bpermute). Exact f32 d2 recompute (difference
//       form), u64 (d2bits<<32|idx) keys, per-chunk Batcher sort-8 + bitonic
//       pad-merge into a sorted-16 register run. Then centroid/cov + f64
//       eigensolve + features, all per-thread.
// ws: xs/ys/zs (295KB) | pts4 AoS + pad (393KB) | cidx u16 [NQ][128] (6.3MB).

#define NPTS 12288
#define NBATCH 2
#define NQ (NPTS * NBATCH)
#define KNN 16
#define NCH 16
#define CHSZ (NPTS / NCH) // 768
#define MKEEP 8
#define QBLK (NQ / 256) // 96

typedef unsigned long long u64;
typedef unsigned short u16;
typedef unsigned int u32;

#define SWAPU(a, b) { u32 _lo = min(a, b); u32 _hi = max(a, b); a = _lo; b = _hi; }
#define SWAP64(a, b) { u64 _lo = (a) < (b) ? (a) : (b); u64 _hi = (a) < (b) ? (b) : (a); a = _lo; b = _hi; }
#define MIN64(a, b) ((a) < (b) ? (a) : (b))
#define DIST(dst, px, py, pz) { float _dx = Qx - (px); float _dy = Qy - (py); float _dz = Qz - (pz); \
                                dst = fmaf(_dz, _dz, fmaf(_dy, _dy, _dx * _dx)); }
#define KEY(kk, dd, rel) { kk = (__float_as_uint(dd) & 0xFFFFFC00u) | (u32)(rel); }

__global__ __launch_bounds__(256) void pack_kernel(const float* __restrict__ xyz,
                                                   float* __restrict__ xs,
                                                   float* __restrict__ ys,
                                                   float* __restrict__ zs,
                                                   float4* __restrict__ pts4) {
  int i = blockIdx.x * 256 + threadIdx.x;
  if (i < NQ) {
    float x = xyz[3 * i + 0], y = xyz[3 * i + 1], z = xyz[3 * i + 2];
    xs[i] = x; ys[i] = y; zs[i] = z;
    pts4[i] = make_float4(x, y, z, fmaf(z, z, fmaf(y, y, x * x)));
  }
}

// One thread = one query x one chunk of 768 candidates. Candidate loads are
// uniform (blockIdx-derived address only) -> scalar pipe. Branchless top-8.
__global__ __launch_bounds__(256) void knn_kernel(const float4* __restrict__ pts4,
                                                  u16* __restrict__ cidx) {
  int bid = blockIdx.x;
  int qb = bid % QBLK;
  int chk = bid / QBLK;
  int q0 = qb * 256;                    // uniform
  int b = q0 / NPTS;                    // uniform (NPTS % 256 == 0)
  int base = b * NPTS + chk * CHSZ;     // uniform
  int q = q0 + threadIdx.x;

  float4 Q = pts4[q];                   // per-lane: x,y,z,|q|^2
  float qq = Q.w;
  float m2x = -2.0f * Q.x, m2y = -2.0f * Q.y, m2z = -2.0f * Q.z;

  const float4* cp = pts4 + base;       // uniform pointer

  u32 r0 = ~0u, r1 = ~0u, r2 = ~0u, r3 = ~0u, r4 = ~0u, r5 = ~0u, r6 = ~0u, r7 = ~0u;

#define SVAL(dst, c) dst = fmaf(m2x, (c).x, fmaf(m2y, (c).y, fmaf(m2z, (c).z, qq + (c).w)));

  // prime batch 0 (uniform loads -> SGPRs)
  float4 a0 = cp[0], a1 = cp[1], a2 = cp[2], a3 = cp[3];
  float4 a4 = cp[4], a5 = cp[5], a6 = cp[6], a7 = cp[7];

#pragma unroll 1
  for (int c0 = 0; c0 < CHSZ; c0 += 8) {
    // prefetch next batch (last iter overreads into the pad)
    float4 n0 = cp[c0 + 8], n1 = cp[c0 + 9], n2 = cp[c0 + 10], n3 = cp[c0 + 11];
    float4 n4 = cp[c0 + 12], n5 = cp[c0 + 13], n6 = cp[c0 + 14], n7 = cp[c0 + 15];

    float e0, e1, e2, e3, e4, e5, e6, e7;
    SVAL(e0, a0) SVAL(e1, a1) SVAL(e2, a2) SVAL(e3, a3)
    SVAL(e4, a4) SVAL(e5, a5) SVAL(e6, a6) SVAL(e7, a7)
    u32 d0, d1, d2, d3, d4, d5, d6, d7;
    KEY(d0, e0, c0 + 0); KEY(d1, e1, c0 + 1); KEY(d2, e2, c0 + 2); KEY(d3, e3, c0 + 3);
    KEY(d4, e4, c0 + 4); KEY(d5, e5, c0 + 5); KEY(d6, e6, c0 + 6); KEY(d7, e7, c0 + 7);
    // Batcher sort-8 ascending (19 CEs)
    SWAPU(d0, d1) SWAPU(d2, d3) SWAPU(d4, d5) SWAPU(d6, d7)
    SWAPU(d0, d2) SWAPU(d1, d3) SWAPU(d4, d6) SWAPU(d5, d7)
    SWAPU(d1, d2) SWAPU(d5, d6)
    SWAPU(d0, d4) SWAPU(d1, d5) SWAPU(d2, d6) SWAPU(d3, d7)
    SWAPU(d2, d4) SWAPU(d3, d5)
    SWAPU(d1, d2) SWAPU(d3, d4) SWAPU(d5, d6)
    // keep lowest-8 of (run, batch): cross-min -> bitonic resort (12 CEs)
    u32 m0 = min(r0, d7), m1 = min(r1, d6), m2 = min(r2, d5), m3 = min(r3, d4);
    u32 m4 = min(r4, d3), m5 = min(r5, d2), m6 = min(r6, d1), m7 = min(r7, d0);
    SWAPU(m0, m4) SWAPU(m1, m5) SWAPU(m2, m6) SWAPU(m3, m7)
    SWAPU(m0, m2) SWAPU(m1, m3) SWAPU(m4, m6) SWAPU(m5, m7)
    SWAPU(m0, m1) SWAPU(m2, m3) SWAPU(m4, m5) SWAPU(m6, m7)
    r0 = m0; r1 = m1; r2 = m2; r3 = m3; r4 = m4; r5 = m5; r6 = m6; r7 = m7;

    a0 = n0; a1 = n1; a2 = n2; a3 = n3; a4 = n4; a5 = n5; a6 = n6; a7 = n7;
  }
#undef SVAL

  // epilogue: strip to global-in-batch indices, pack 8 x u16 = 16B store
  u32 cb = (u32)(chk * CHSZ);
  uint4 w;
  w.x = (cb + (r0 & 1023u)) | ((cb + (r1 & 1023u)) << 16);
  w.y = (cb + (r2 & 1023u)) | ((cb + (r3 & 1023u)) << 16);
  w.z = (cb + (r4 & 1023u)) | ((cb + (r5 & 1023u)) << 16);
  w.w = (cb + (r6 & 1023u)) | ((cb + (r7 & 1023u)) << 16);
  *(uint4*)(cidx + (size_t)q * (NCH * MKEEP) + chk * MKEEP) = w;
}

// One THREAD per query: exact u64 selection fully in registers, no shuffles.
__global__ __launch_bounds__(256) void feat_kernel(const float* __restrict__ xs,
                                                   const float* __restrict__ ys,
                                                   const float* __restrict__ zs,
                                                   const float* __restrict__ normals,
                                                   const u16* __restrict__ cidx,
                                                   float* __restrict__ out) {
  int t = blockIdx.x * 256 + threadIdx.x; // query 0..NQ
  int b = t / NPTS;
  int qi = t - b * NPTS;
  int bbase = b * NPTS;

  float Qx = xs[t], Qy = ys[t], Qz = zs[t];

  const uint4* crow = (const uint4*)(cidx + (size_t)t * (NCH * MKEEP));

  u64 run[KNN];
#pragma unroll
  for (int i = 0; i < KNN; ++i) run[i] = ~0ULL;

#pragma unroll 1
  for (int ch = 0; ch < NCH; ++ch) {
    uint4 w = crow[ch]; // 8 u16 candidate indices
    int ix[8];
    ix[0] = (int)(w.x & 0xFFFFu); ix[1] = (int)(w.x >> 16);
    ix[2] = (int)(w.y & 0xFFFFu); ix[3] = (int)(w.y >> 16);
    ix[4] = (int)(w.z & 0xFFFFu); ix[5] = (int)(w.z >> 16);
    ix[6] = (int)(w.w & 0xFFFFu); ix[7] = (int)(w.w >> 16);
    u64 s0, s1, s2, s3, s4, s5, s6, s7;
#define MK(sv, j) { int _i = ix[j]; float _d; DIST(_d, xs[bbase + _i], ys[bbase + _i], zs[bbase + _i]); \
                    sv = ((u64)__float_as_uint(_d) << 32) | (u32)_i; if (_i == qi) sv = ~0ULL; }
    MK(s0, 0) MK(s1, 1) MK(s2, 2) MK(s3, 3) MK(s4, 4) MK(s5, 5) MK(s6, 6) MK(s7, 7)
#undef MK
    // Batcher sort-8 ascending (19 CEs on u64)
    SWAP64(s0, s1) SWAP64(s2, s3) SWAP64(s4, s5) SWAP64(s6, s7)
    SWAP64(s0, s2) SWAP64(s1, s3) SWAP64(s4, s6) SWAP64(s5, s7)
    SWAP64(s1, s2) SWAP64(s5, s6)
    SWAP64(s0, s4) SWAP64(s1, s5) SWAP64(s2, s6) SWAP64(s3, s7)
    SWAP64(s2, s4) SWAP64(s3, s5)
    SWAP64(s1, s2) SWAP64(s3, s4) SWAP64(s5, s6)
    // pad-merge sorted-8 into sorted-16 run: halver (run asc, s asc padded INF)
    run[8]  = MIN64(run[8],  s7);
    run[9]  = MIN64(run[9],  s6);
    run[10] = MIN64(run[10], s5);
    run[11] = MIN64(run[11], s4);
    run[12] = MIN64(run[12], s3);
    run[13] = MIN64(run[13], s2);
    run[14] = MIN64(run[14], s1);
    run[15] = MIN64(run[15], s0);
    // run is now bitonic: bitonic-merge-16 ascending (4 stages x 8 CE)
#pragma unroll
    for (int j = 8; j >= 1; j >>= 1) {
#pragma unroll
      for (int i = 0; i < KNN; ++i) {
        if ((i & j) == 0) { SWAP64(run[i], run[i | j]) }
      }
    }
  }

  // gather the 16 selected neighbors (low words of run = indices)
  float nx[KNN], ny[KNN], nz[KNN];
  float sx = 0.f, sy = 0.f, sz = 0.f;
#pragma unroll
  for (int i = 0; i < KNN; ++i) {
    int ni = (int)(u32)run[i];
    float px = xs[bbase + ni], py = ys[bbase + ni], pz = zs[bbase + ni];
    nx[i] = px; ny[i] = py; nz[i] = pz;
    sx += px; sy += py; sz += pz;
  }
  const float invK = 1.0f / 16.0f;
  float cx = sx * invK, cy = sy * invK, cz = sz * invK;

  float c00 = 0.f, c01 = 0.f, c02 = 0.f, c11 = 0.f, c12 = 0.f, c22 = 0.f;
#pragma unroll
  for (int i = 0; i < KNN; ++i) {
    float dx = nx[i] - cx, dy = ny[i] - cy, dz = nz[i] - cz;
    c00 += dx * dx; c01 += dx * dy; c02 += dx * dz;
    c11 += dy * dy; c12 += dy * dz; c22 += dz * dz;
  }
  const float inv15 = 1.0f / 15.0f;
  c00 *= inv15; c01 *= inv15; c02 *= inv15;
  c11 *= inv15; c12 *= inv15; c22 *= inv15;

  // f64 analytic eigensolve (smallest eigenvalue) — proven path.
  double a00 = c00, a01 = c01, a02 = c02, a11 = c11, a12 = c12, a22 = c22;
  double tr = a00 + a11 + a22;
  double qm = tr * (1.0 / 3.0);
  double p1 = a01 * a01 + a02 * a02 + a12 * a12;
  double b00 = a00 - qm, b11 = a11 - qm, b22 = a22 - qm;
  double p2 = b00 * b00 + b11 * b11 + b22 * b22 + 2.0 * p1;
  double lmin = qm;
  if (p2 > 0.0) {
    double p = sqrt(p2 * (1.0 / 6.0));
    double ip = 1.0 / p;
    double q00 = b00 * ip, q01 = a01 * ip, q02 = a02 * ip;
    double q11 = b11 * ip, q12 = a12 * ip, q22 = b22 * ip;
    double det = q00 * (q11 * q22 - q12 * q12) - q01 * (q01 * q22 - q12 * q02) +
                 q02 * (q01 * q12 - q11 * q02);
    double r = 0.5 * det;
    r = r < -1.0 ? -1.0 : (r > 1.0 ? 1.0 : r);
    double phi = acos(r) * (1.0 / 3.0);
    lmin = qm + 2.0 * p * cos(phi + 2.0943951023931953);
  }

  // eigenvector: cross products of rows of (A - lmin I), pick largest.
  double m00 = a00 - lmin, m11 = a11 - lmin, m22 = a22 - lmin;
  double v0x = a01 * a12 - a02 * m11;
  double v0y = a02 * a01 - m00 * a12;
  double v0z = m00 * m11 - a01 * a01;
  double v1x = a01 * m22 - a02 * a12;
  double v1y = a02 * a02 - m00 * m22;
  double v1z = m00 * a12 - a01 * a02;
  double v2x = m11 * m22 - a12 * a12;
  double v2y = a12 * a02 - a01 * m22;
  double v2z = a01 * a12 - m11 * a02;
  double n0 = v0x * v0x + v0y * v0y + v0z * v0z;
  double n1 = v1x * v1x + v1y * v1y + v1z * v1z;
  double n2 = v2x * v2x + v2y * v2y + v2z * v2z;
  double vx, vy, vz, nn;
  if (n0 >= n1 && n0 >= n2) { vx = v0x; vy = v0y; vz = v0z; nn = n0; }
  else if (n1 >= n2)        { vx = v1x; vy = v1y; vz = v1z; nn = n1; }
  else                      { vx = v2x; vy = v2y; vz = v2z; nn = n2; }
  if (nn < 1e-60) { vx = 0.0; vy = 0.0; vz = 1.0; nn = 1.0; }
  double inn = 1.0 / sqrt(nn);
  float vxf = (float)(vx * inn), vyf = (float)(vy * inn), vzf = (float)(vz * inn);

  // roughness: mean |centered . v|
  float s = 0.f;
#pragma unroll
  for (int i = 0; i < KNN; ++i) {
    s += fabsf((nx[i] - cx) * vxf + (ny[i] - cy) * vyf + (nz[i] - cz) * vzf);
  }

  float nrx = normals[3 * (size_t)t + 0];
  float nry = normals[3 * (size_t)t + 1];
  float nrz = normals[3 * (size_t)t + 2];
  float dot = vxf * nrx + vyf * nry + vzf * nrz;
  float cons = fabsf(dot);
  float trf = c00 + c11 + c22;
  float curv = (float)lmin / fmaxf(trf, 1e-8f);
  float* o = out + (size_t)t * 6;
  o[0] = cons;
  o[1] = nrx;
  o[2] = nry;
  o[3] = nrz;
  o[4] = curv;
  o[5] = s * invK;
}

extern "C" void kernel_launch(void* const* d_in, const int* in_sizes, int n_in,
                              void* d_out, int out_size, void* d_ws, size_t ws_size,
                              hipStream_t stream) {
  const float* xyz = (const float*)d_in[0];
  const float* normals = (const float*)d_in[1];
  float* out = (float*)d_out;

  float* xs = (float*)d_ws;
  float* ys = xs + NQ;
  float* zs = ys + NQ;
  float4* pts4 = (float4*)(zs + NQ);          // NQ float4 + 8 pad
  u16* cidx = (u16*)(pts4 + NQ + 8);          // NQ*128 u16 = 6.3MB

  pack_kernel<<<NQ / 256, 256, 0, stream>>>(xyz, xs, ys, zs, pts4);
  knn_kernel<<<QBLK * NCH, 256, 0, stream>>>(pts4, cidx);
  feat_kernel<<<NQ / 256, 256, 0, stream>>>(xs, ys, zs, normals, cidx, out);
}